// Round 18
// baseline (41.237 us; speedup 1.0000x reference)
//
#include <hip/hip_runtime.h>
#include <math.h>

// Rational-quadratic spline inverse log-prob (Durkan et al.), inverse pass only.
// out = log(0.5) + where(inside, log|dx/dy|, 0)
//
// IDENTITY (R13): |dx/dy| = h*denom / (dl*sqrt(disc)), denom = dl + T*th*(1-th).
//
// R18 = R16's EXACT precompute/layout (passed, absmax 0.047) + SCALAR main math
// (R17's hypothesis: v_pk register-pair marshaling was ~2x v_mov glue).
// NUMERICS RULE (R9/R12/R17 failures vs R10/R13-R16 passes): e_lo, h, dy must
// be f32; only {dl, d0, T} tolerate f16 (coherent param perturbation).
//
// Record = {e_lo f32, h f32, dl|d0 f16x2, T f16, pad} @ stride-5 dwords (20 B):
//   gcd(5,32)=1 -> bank-spread, conflict-light random-k gather.
// hint16[slot] = k | split<<7: arithmetic bin select (2-level LDS chain);
//   k2 = k + (q > split), q = low 9 bits of (xc+1)*2^18. Mis-select <= 1
//   quantum (3.8e-6) is safe (log|dx/dy| continuous at knots);
//   dy = med3(xc-e_lo, 0, h) keeps theta in [0,1] exactly.
//
// tab byte layout (37,024 B staged):
//   rec    @ 0     : 8ch x 129 x 20 B (entry 128 = safe pad, unreachable)
//   hint16 @ 20640 : 8ch x 1024 u16

#define NB 128
#define NCH 8
#define NSLOT 1024
#define HINT_B 20640
#define TAB_FLOATS 9256   // 37,024 B

static __device__ inline unsigned f2h(float v) {
    union { _Float16 h; unsigned short u; } c;
    c.h = (_Float16)v;
    return (unsigned)c.u;
}
static __device__ inline float h16lo(unsigned u) {
    union { unsigned short s; _Float16 h; } c; c.s = (unsigned short)(u & 0xffffu);
    return (float)c.h;
}
static __device__ inline float h16hi(unsigned u) {
    union { unsigned short s; _Float16 h; } c; c.s = (unsigned short)(u >> 16);
    return (float)c.h;
}

__global__ __launch_bounds__(128) void spline_precompute(
    const float* __restrict__ uw, const float* __restrict__ uh,
    const float* __restrict__ ud, float* __restrict__ ws)
{
    const int c = blockIdx.x;   // channel
    const int i = threadIdx.x;  // bin
    __shared__ float red[128];
    __shared__ float scan[128];
    __shared__ float cum[129];
    __shared__ float wdt[128];
    __shared__ float sdv[129];
    const float DEFAULT_INIT = logf(expf(1.0f - 1e-3f) - 1.0f);

    // ---------------- widths: softmax(uw*10) -> sizes -> cumsum -> knots ----
    float v = uw[c * NB + i] * 10.0f;
    red[i] = v; __syncthreads();
    #pragma unroll
    for (int s = 64; s >= 1; s >>= 1) { if (i < s) red[i] = fmaxf(red[i], red[i + s]); __syncthreads(); }
    float ex = expf(v - red[0]);
    __syncthreads();
    red[i] = ex; __syncthreads();
    #pragma unroll
    for (int s = 64; s >= 1; s >>= 1) { if (i < s) red[i] += red[i + s]; __syncthreads(); }
    float sz = 1e-3f + (1.0f - 1e-3f * NB) * (ex / red[0]);
    __syncthreads();
    scan[i] = sz;
    for (int off = 1; off < NB; off <<= 1) {
        __syncthreads();
        float t = (i >= off) ? scan[i - off] : 0.0f;
        __syncthreads();
        scan[i] += t;
    }
    __syncthreads();
    if (i == 0) cum[0] = -1.0f;
    cum[i + 1] = (i == NB - 1) ? 1.0f : fmaf(2.0f, scan[i], -1.0f);
    __syncthreads();
    wdt[i] = cum[i + 1] - cum[i];
    __syncthreads();   // cum gets reused below

    // ---------------- heights: same pipeline on uh*10 ----------------------
    v = uh[c * NB + i] * 10.0f;
    red[i] = v; __syncthreads();
    #pragma unroll
    for (int s = 64; s >= 1; s >>= 1) { if (i < s) red[i] = fmaxf(red[i], red[i + s]); __syncthreads(); }
    ex = expf(v - red[0]);
    __syncthreads();
    red[i] = ex; __syncthreads();
    #pragma unroll
    for (int s = 64; s >= 1; s >>= 1) { if (i < s) red[i] += red[i + s]; __syncthreads(); }
    sz = 1e-3f + (1.0f - 1e-3f * NB) * (ex / red[0]);
    __syncthreads();
    scan[i] = sz;
    for (int off = 1; off < NB; off <<= 1) {
        __syncthreads();
        float t = (i >= off) ? scan[i - off] : 0.0f;
        __syncthreads();
        scan[i] += t;
    }
    __syncthreads();
    if (i == 0) cum[0] = -1.0f;
    cum[i + 1] = (i == NB - 1) ? 1.0f : fmaf(2.0f, scan[i], -1.0f);

    // ---------------- derivatives: MIN_D + softplus(pad(ud)) ---------------
    float u0 = (i == 0) ? DEFAULT_INIT : ud[c * (NB - 1) + i - 1];
    sdv[i] = 1e-3f + log1pf(expf(u0));
    if (i == NB - 1) sdv[NB] = 1e-3f + log1pf(expf(DEFAULT_INIT));
    __syncthreads();

    // ---------------- emit tables ------------------------------------------
    float hh  = cum[i + 1] - cum[i];     // SAME subtraction class as reference
    float idl = hh / wdt[i];
    float d0v = sdv[i], d1v = sdv[i + 1];
    float Tv  = d0v + d1v - 2.0f * idl;

    unsigned* g_rec = reinterpret_cast<unsigned*>(ws);
    const int rw = (c * 129 + i) * 5;
    g_rec[rw]     = __float_as_uint(cum[i]);
    g_rec[rw + 1] = __float_as_uint(hh);
    g_rec[rw + 2] = f2h(idl) | (f2h(d0v) << 16);
    g_rec[rw + 3] = f2h(Tv);
    g_rec[rw + 4] = 0u;
    if (i == NB - 1) {   // pad entry 128 (unreachable; keep defined & safe)
        const int pw = (c * 129 + NB) * 5;
        g_rec[pw]     = __float_as_uint(1.0f);
        g_rec[pw + 1] = __float_as_uint(1.0f);
        g_rec[pw + 2] = f2h(1.0f) | (f2h(1.0f) << 16);
        g_rec[pw + 3] = 0u;
        g_rec[pw + 4] = 0u;
    }

    // hint16[s] = k | split<<7.  k = max bin with cum[k] <= slot_left.
    // split = clamp(ceil((cum[k+1]-left)*2^18) - 1, 0, 511); advance iff q>split.
    // No knot in slot -> X >= 512 -> split=511 -> never advances (strict >).
    unsigned short* g_hint = reinterpret_cast<unsigned short*>(
        reinterpret_cast<char*>(ws) + HINT_B);
    for (int s = i; s < NSLOT; s += NB) {
        float left = (float)s * (2.0f / NSLOT) - 1.0f;
        int k = 0;
        #pragma unroll
        for (int st = 64; st >= 1; st >>= 1) {   // 64+...+1 = 127, stays in [0,127]
            int t = k + st;
            if (cum[t] <= left) k = t;
        }
        float X = (cum[k + 1] - left) * 262144.0f;   // (e1-left)/slot_w * 512
        int split = (int)ceilf(X) - 1;
        split = split < 0 ? 0 : (split > 511 ? 511 : split);
        g_hint[c * NSLOT + s] = (unsigned short)(k | (split << 7));
    }
}

__global__ __launch_bounds__(256, 4) void spline_main(
    const float4* __restrict__ x4, float4* __restrict__ out4,
    const float* __restrict__ ws, int npair)
{
    __shared__ __align__(16) float tab[TAB_FLOATS];
    {
        float4* dst = reinterpret_cast<float4*>(tab);
        const float4* src = reinterpret_cast<const float4*>(ws);
        for (int t = threadIdx.x; t < TAB_FLOATS / 4; t += 256) dst[t] = src[t];
    }
    __syncthreads();
    const unsigned* rec = reinterpret_cast<const unsigned*>(tab);
    const unsigned short* hint = reinterpret_cast<const unsigned short*>(
        reinterpret_cast<const char*>(tab) + HINT_B);

    const float LOG_HALF = -0.6931471805599453f;
    const float LN2 = 0.6931471805599453f;
    const int tid = blockIdx.x * 256 + threadIdx.x;
    const int stride = gridDim.x * 256;

    float4 pfa, pfb;
    if (tid < npair) { pfa = x4[2 * tid]; pfb = x4[2 * tid + 1]; }

    for (int i = tid; i < npair; i += stride) {
        float4 xa = pfa, xb = pfb;
        int inx = i + stride;
        inx = (inx < npair) ? inx : i;          // safe redundant prefetch on last iter
        pfa = x4[2 * inx];
        pfb = x4[2 * inx + 1];

        float xs[8] = {xa.x, xa.y, xa.z, xa.w, xb.x, xb.y, xb.z, xb.w};
        float rs[8];

        #pragma unroll
        for (int j = 0; j < 8; ++j) {           // j == channel (flat % 8)
            float xin = xs[j];
            float xc = __builtin_amdgcn_fmed3f(xin, -1.0f, 1.0f);
            float g = fmaf(xc, 262144.0f, 262144.0f);    // (xc+1)*2^18
            int gi = (int)g;
            gi = gi > 524287 ? 524287 : gi;
            int q = gi & 511;
            unsigned hv = hint[j * NSLOT + (gi >> 9)];
            int k2 = (int)(hv & 127u) + ((q > (int)(hv >> 7)) ? 1 : 0);

            const unsigned* p = rec + (j * 129 + k2) * 5;   // stride-5: bank-spread
            float e_lo = __uint_as_float(p[0]);
            float h    = __uint_as_float(p[1]);
            unsigned w2 = p[2];                  // dl | d0
            float T    = h16lo(p[3]);
            float dl = h16lo(w2), d0 = h16hi(w2);

            float dy  = __builtin_amdgcn_fmed3f(xc - e_lo, 0.0f, h); // theta in [0,1]
            float dyt = dy * T;
            float a   = fmaf(h, dl - d0, dyt);
            float b   = fmaf(h, d0, -dyt);
            float cp  = dl * dy;
            float a4  = 4.0f * a;
            float disc = fmaxf(fmaf(a4, cp, b * b), 0.0f);
            float sq  = __builtin_amdgcn_sqrtf(disc);
            float t2  = b + sq;
            float uu  = cp + cp;
            float t2s = t2 * t2;
            float denb = fmaf(T * uu, t2 - uu, dl * t2s);
            float numf = h * denb;
            float den  = (dl * sq) * t2s;
            float la = __log2f(numf) - __log2f(den);
            float lm = (xin == xc) ? LN2 : 0.0f;   // inside <=> clamp no-op
            rs[j] = fmaf(lm, la, LOG_HALF);
        }

        out4[2 * i]     = make_float4(rs[0], rs[1], rs[2], rs[3]);
        out4[2 * i + 1] = make_float4(rs[4], rs[5], rs[6], rs[7]);
    }
}

extern "C" void kernel_launch(void* const* d_in, const int* in_sizes, int n_in,
                              void* d_out, int out_size, void* d_ws, size_t ws_size,
                              hipStream_t stream) {
    const float* x  = (const float*)d_in[0];
    const float* uw = (const float*)d_in[1];
    const float* uh = (const float*)d_in[2];
    const float* ud = (const float*)d_in[3];
    float* ws = (float*)d_ws;

    spline_precompute<<<NCH, NB, 0, stream>>>(uw, uh, ud, ws);

    const int npair = out_size / 8;   // 2,097,152 = 2048*256*4
    spline_main<<<2048, 256, 0, stream>>>(
        (const float4*)x, (float4*)d_out, ws, npair);
}

// Round 19
// 39.977 us; speedup vs baseline: 1.0315x; 1.0315x over previous
//
#include <hip/hip_runtime.h>
#include <math.h>

// Rational-quadratic spline inverse log-prob (Durkan et al.), inverse pass only.
// out = log(0.5) + where(inside, log|dx/dy|, 0)
//
// IDENTITY (R13): |dx/dy| = h*denom / (dl*sqrt(disc)), denom = dl + T*th*(1-th).
//
// R19: ISSUE-COUNT reduction. (1) 16 B record {e_lo f32, h f32, dl|d0 f16x2,
// T f16} -> ONE ds_read_b128 per element (2 LDS ops total incl. u16 hint),
// addressing = k2<<4 + imm offset. 16B stride = 8-way bank conflict, proven
// time-neutral (R14 vs R15 A/B). (2) Barrier-free precompute: 1 wave/channel,
// shfl-based softmax/scan (2 bins per lane), 1 barrier total.
// NUMERICS RULE (R9/R12/R17 fails): e_lo, h, dy f32; only {dl,d0,T} f16.
//
// tab byte layout (32,896 B staged):
//   rec    @ 0     : 8ch x 129 x 16 B (entry 128 = safe pad, unreachable)
//   hint16 @ 16512 : 8ch x 1024 u16  (k | split<<7; advance iff q > split)

#define NB 128
#define NCH 8
#define NSLOT 1024
#define HINT_B 16512
#define TAB_FLOATS 8224   // 32,896 B

static __device__ inline unsigned f2h(float v) {
    union { _Float16 h; unsigned short u; } c;
    c.h = (_Float16)v;
    return (unsigned)c.u;
}
static __device__ inline float h16lo(unsigned u) {
    union { unsigned short s; _Float16 h; } c; c.s = (unsigned short)(u & 0xffffu);
    return (float)c.h;
}
static __device__ inline float h16hi(unsigned u) {
    union { unsigned short s; _Float16 h; } c; c.s = (unsigned short)(u >> 16);
    return (float)c.h;
}

__global__ __launch_bounds__(64) void spline_precompute(
    const float* __restrict__ uw, const float* __restrict__ uh,
    const float* __restrict__ ud, float* __restrict__ ws)
{
    const int c = blockIdx.x;        // channel
    const int l = threadIdx.x;       // lane 0..63, owns bins 2l, 2l+1
    const int i0 = 2 * l, i1 = i0 + 1;
    const float DEF = logf(expf(1.0f - 1e-3f) - 1.0f);
    const float DSP = 1e-3f + log1pf(expf(DEF));   // softplus chain at DEFAULT (= 1.0)

    // ---------------- widths: softmax(uw*10) -> sizes -> exclusive prefix --
    float a0 = uw[c * NB + i0] * 10.0f, a1 = uw[c * NB + i1] * 10.0f;
    float mw = fmaxf(a0, a1);
    #pragma unroll
    for (int off = 1; off < 64; off <<= 1) mw = fmaxf(mw, __shfl_xor(mw, off, 64));
    float ew0 = expf(a0 - mw), ew1 = expf(a1 - mw);
    float sw = ew0 + ew1;
    #pragma unroll
    for (int off = 1; off < 64; off <<= 1) sw += __shfl_xor(sw, off, 64);
    float rw = 1.0f / sw;
    float zw0 = fmaf(0.872f * ew0, rw, 1e-3f);   // 1-1e-3*128 = 0.872
    float zw1 = fmaf(0.872f * ew1, rw, 1e-3f);
    float tw = zw0 + zw1, Iw = tw;
    #pragma unroll
    for (int off = 1; off < 64; off <<= 1) {
        float u = __shfl_up(Iw, off, 64);
        if (l >= off) Iw += u;
    }
    float Ew = Iw - tw;                          // exclusive prefix (cumW[i0])
    float cw1 = Ew + zw0;                        // cumW[i1]
    float w0 = 2.0f * zw0;
    float w1 = (i1 == NB - 1) ? 2.0f * (1.0f - cw1) : 2.0f * zw1;

    // ---------------- heights: same pipeline on uh*10 -----------------------
    float b0 = uh[c * NB + i0] * 10.0f, b1 = uh[c * NB + i1] * 10.0f;
    float mh = fmaxf(b0, b1);
    #pragma unroll
    for (int off = 1; off < 64; off <<= 1) mh = fmaxf(mh, __shfl_xor(mh, off, 64));
    float eh0 = expf(b0 - mh), eh1 = expf(b1 - mh);
    float sh = eh0 + eh1;
    #pragma unroll
    for (int off = 1; off < 64; off <<= 1) sh += __shfl_xor(sh, off, 64);
    float rh = 1.0f / sh;
    float zh0 = fmaf(0.872f * eh0, rh, 1e-3f);
    float zh1 = fmaf(0.872f * eh1, rh, 1e-3f);
    float th = zh0 + zh1, Ih = th;
    #pragma unroll
    for (int off = 1; off < 64; off <<= 1) {
        float u = __shfl_up(Ih, off, 64);
        if (l >= off) Ih += u;
    }
    float Eh = Ih - th;                          // cumH[i0]
    float ch1 = Eh + zh0;                        // cumH[i1]
    float elo0 = fmaf(2.0f, Eh, -1.0f);          // y-knot of bin i0 (i0=0 -> -1 exact)
    float elo1 = fmaf(2.0f, ch1, -1.0f);
    float h0 = 2.0f * zh0;
    float h1 = (i1 == NB - 1) ? 2.0f * (1.0f - ch1) : 2.0f * zh1;

    // ---------------- derivatives: MIN_D + softplus(pad(ud)) ----------------
    float du0 = (i0 == 0) ? DEF : ud[c * (NB - 1) + i0 - 1];
    float du1 = ud[c * (NB - 1) + i1 - 1];
    float s0 = 1e-3f + log1pf(expf(du0));        // sdv[i0]
    float s1 = 1e-3f + log1pf(expf(du1));        // sdv[i1]
    float s2 = __shfl_down(s0, 1, 64);           // sdv[i1+1] from lane l+1
    if (l == 63) s2 = DSP;                       // sdv[128]

    float dl0 = h0 / w0, dl1 = h1 / w1;
    float T0 = s0 + s1 - 2.0f * dl0;
    float T1 = s1 + s2 - 2.0f * dl1;

    // ---------------- emit records (16 B, single b128-readable) -------------
    uint4* g_rec = reinterpret_cast<uint4*>(ws);
    g_rec[c * 129 + i0] = make_uint4(__float_as_uint(elo0), __float_as_uint(h0),
                                     f2h(dl0) | (f2h(s0) << 16), f2h(T0));
    g_rec[c * 129 + i1] = make_uint4(__float_as_uint(elo1), __float_as_uint(h1),
                                     f2h(dl1) | (f2h(s1) << 16), f2h(T1));
    if (l == 63)   // pad entry 128 (unreachable; keep defined & safe)
        g_rec[c * 129 + 128] = make_uint4(__float_as_uint(1.0f), __float_as_uint(1.0f),
                                          f2h(1.0f) | (f2h(1.0f) << 16), 0u);

    // ---------------- knots to LDS, then hint16 table -----------------------
    __shared__ float kn[129];
    kn[i0] = elo0;
    kn[i1] = elo1;
    if (l == 63) kn[128] = 1.0f;
    __syncthreads();

    // hint16[s] = k | split<<7.  k = max bin with kn[k] <= slot_left.
    // split = clamp(ceil((kn[k+1]-left)*2^18) - 1, 0, 511); advance iff q>split.
    unsigned short* g_hint = reinterpret_cast<unsigned short*>(
        reinterpret_cast<char*>(ws) + HINT_B);
    for (int s = l; s < NSLOT; s += 64) {
        float left = (float)s * (2.0f / NSLOT) - 1.0f;
        int k = 0;
        #pragma unroll
        for (int st = 64; st >= 1; st >>= 1) {   // 64+...+1 = 127, stays in [0,127]
            int t = k + st;
            if (kn[t] <= left) k = t;
        }
        float X = (kn[k + 1] - left) * 262144.0f;
        int split = (int)ceilf(X) - 1;
        split = split < 0 ? 0 : (split > 511 ? 511 : split);
        g_hint[c * NSLOT + s] = (unsigned short)(k | (split << 7));
    }
}

__global__ __launch_bounds__(256, 4) void spline_main(
    const float4* __restrict__ x4, float4* __restrict__ out4,
    const float* __restrict__ ws, int npair)
{
    __shared__ __align__(16) float tab[TAB_FLOATS];
    {
        float4* dst = reinterpret_cast<float4*>(tab);
        const float4* src = reinterpret_cast<const float4*>(ws);
        for (int t = threadIdx.x; t < TAB_FLOATS / 4; t += 256) dst[t] = src[t];
    }
    __syncthreads();
    const uint4* rp = reinterpret_cast<const uint4*>(tab);
    const unsigned short* hint = reinterpret_cast<const unsigned short*>(
        reinterpret_cast<const char*>(tab) + HINT_B);

    const float LOG_HALF = -0.6931471805599453f;
    const float LN2 = 0.6931471805599453f;
    const int tid = blockIdx.x * 256 + threadIdx.x;
    const int stride = gridDim.x * 256;

    float4 pfa, pfb;
    if (tid < npair) { pfa = x4[2 * tid]; pfb = x4[2 * tid + 1]; }

    for (int i = tid; i < npair; i += stride) {
        float4 xa = pfa, xb = pfb;
        int inx = i + stride;
        inx = (inx < npair) ? inx : i;          // safe redundant prefetch on last iter
        pfa = x4[2 * inx];
        pfb = x4[2 * inx + 1];

        float xs[8] = {xa.x, xa.y, xa.z, xa.w, xb.x, xb.y, xb.z, xb.w};
        float rs[8];

        #pragma unroll
        for (int j = 0; j < 8; ++j) {           // j == channel (flat % 8)
            float xin = xs[j];
            float xc = __builtin_amdgcn_fmed3f(xin, -1.0f, 1.0f);
            float g = fmaf(xc, 262144.0f, 262144.0f);    // (xc+1)*2^18
            int gi = (int)g;
            gi = gi > 524287 ? 524287 : gi;
            int q = gi & 511;
            unsigned hv = hint[j * NSLOT + (gi >> 9)];
            int k2 = (int)(hv & 127u) + ((q > (int)(hv >> 7)) ? 1 : 0);

            uint4 pr = rp[j * 129 + k2];         // ONE ds_read_b128
            float e_lo = __uint_as_float(pr.x);
            float h    = __uint_as_float(pr.y);
            float dl = h16lo(pr.z), d0 = h16hi(pr.z);
            float T  = h16lo(pr.w);

            float dy  = __builtin_amdgcn_fmed3f(xc - e_lo, 0.0f, h); // theta in [0,1]
            float dyt = dy * T;
            float a   = fmaf(h, dl - d0, dyt);
            float b   = fmaf(h, d0, -dyt);
            float cp  = dl * dy;
            float a4  = 4.0f * a;
            float disc = fmaxf(fmaf(a4, cp, b * b), 0.0f);
            float sq  = __builtin_amdgcn_sqrtf(disc);
            float t2  = b + sq;
            float uu  = cp + cp;
            float t2s = t2 * t2;
            float denb = fmaf(T * uu, t2 - uu, dl * t2s);
            float numf = h * denb;
            float den  = (dl * sq) * t2s;
            float la = __log2f(numf) - __log2f(den);
            float lm = (xin == xc) ? LN2 : 0.0f;   // inside <=> clamp no-op
            rs[j] = fmaf(lm, la, LOG_HALF);
        }

        out4[2 * i]     = make_float4(rs[0], rs[1], rs[2], rs[3]);
        out4[2 * i + 1] = make_float4(rs[4], rs[5], rs[6], rs[7]);
    }
}

extern "C" void kernel_launch(void* const* d_in, const int* in_sizes, int n_in,
                              void* d_out, int out_size, void* d_ws, size_t ws_size,
                              hipStream_t stream) {
    const float* x  = (const float*)d_in[0];
    const float* uw = (const float*)d_in[1];
    const float* uh = (const float*)d_in[2];
    const float* ud = (const float*)d_in[3];
    float* ws = (float*)d_ws;

    spline_precompute<<<NCH, 64, 0, stream>>>(uw, uh, ud, ws);

    const int npair = out_size / 8;   // 2,097,152 = 2048*256*4
    spline_main<<<2048, 256, 0, stream>>>(
        (const float4*)x, (float4*)d_out, ws, npair);
}

// Round 20
// 39.350 us; speedup vs baseline: 1.0479x; 1.0159x over previous
//
#include <hip/hip_runtime.h>
#include <math.h>

// Rational-quadratic spline inverse log-prob (Durkan et al.), inverse pass only.
// out = log(0.5) + where(inside, log|dx/dy|, 0)
//
// IDENTITY (R13): |dx/dy| = h*denom / (dl*sqrt(disc)), denom = dl + T*th*(1-th).
//
// R20: VALU trim — record {e_lo f32, h f32, dl f32, d0|T f16x2} (16 B, ONE
// ds_read_b128): kills one v_cvt_f32_f16 per element and makes dl exact
// (accuracy headroom). All else = R19 (passed, absmax 0.047, 40.0 us).
// NUMERICS RULE (R9/R12/R17 fails): e_lo, h, dy, (now dl) f32; {d0,T} f16.
//
// tab byte layout (32,896 B staged):
//   rec    @ 0     : 8ch x 129 x 16 B (entry 128 = safe pad, unreachable)
//   hint16 @ 16512 : 8ch x 1024 u16  (k | split<<7; advance iff q > split)

#define NB 128
#define NCH 8
#define NSLOT 1024
#define HINT_B 16512
#define TAB_FLOATS 8224   // 32,896 B

static __device__ inline unsigned f2h(float v) {
    union { _Float16 h; unsigned short u; } c;
    c.h = (_Float16)v;
    return (unsigned)c.u;
}
static __device__ inline float h16lo(unsigned u) {
    union { unsigned short s; _Float16 h; } c; c.s = (unsigned short)(u & 0xffffu);
    return (float)c.h;
}
static __device__ inline float h16hi(unsigned u) {
    union { unsigned short s; _Float16 h; } c; c.s = (unsigned short)(u >> 16);
    return (float)c.h;
}

__global__ __launch_bounds__(64) void spline_precompute(
    const float* __restrict__ uw, const float* __restrict__ uh,
    const float* __restrict__ ud, float* __restrict__ ws)
{
    const int c = blockIdx.x;        // channel
    const int l = threadIdx.x;       // lane 0..63, owns bins 2l, 2l+1
    const int i0 = 2 * l, i1 = i0 + 1;
    const float DEF = logf(expf(1.0f - 1e-3f) - 1.0f);
    const float DSP = 1e-3f + log1pf(expf(DEF));   // softplus at DEFAULT (= 1.0)

    // ---------------- widths: softmax(uw*10) -> sizes -> exclusive prefix --
    float a0 = uw[c * NB + i0] * 10.0f, a1 = uw[c * NB + i1] * 10.0f;
    float mw = fmaxf(a0, a1);
    #pragma unroll
    for (int off = 1; off < 64; off <<= 1) mw = fmaxf(mw, __shfl_xor(mw, off, 64));
    float ew0 = expf(a0 - mw), ew1 = expf(a1 - mw);
    float sw = ew0 + ew1;
    #pragma unroll
    for (int off = 1; off < 64; off <<= 1) sw += __shfl_xor(sw, off, 64);
    float rw = 1.0f / sw;
    float zw0 = fmaf(0.872f * ew0, rw, 1e-3f);   // 1-1e-3*128 = 0.872
    float zw1 = fmaf(0.872f * ew1, rw, 1e-3f);
    float tw = zw0 + zw1, Iw = tw;
    #pragma unroll
    for (int off = 1; off < 64; off <<= 1) {
        float u = __shfl_up(Iw, off, 64);
        if (l >= off) Iw += u;
    }
    float Ew = Iw - tw;                          // exclusive prefix (cumW[i0])
    float cw1 = Ew + zw0;                        // cumW[i1]
    float w0 = 2.0f * zw0;
    float w1 = (i1 == NB - 1) ? 2.0f * (1.0f - cw1) : 2.0f * zw1;

    // ---------------- heights: same pipeline on uh*10 -----------------------
    float b0 = uh[c * NB + i0] * 10.0f, b1 = uh[c * NB + i1] * 10.0f;
    float mh = fmaxf(b0, b1);
    #pragma unroll
    for (int off = 1; off < 64; off <<= 1) mh = fmaxf(mh, __shfl_xor(mh, off, 64));
    float eh0 = expf(b0 - mh), eh1 = expf(b1 - mh);
    float sh = eh0 + eh1;
    #pragma unroll
    for (int off = 1; off < 64; off <<= 1) sh += __shfl_xor(sh, off, 64);
    float rh = 1.0f / sh;
    float zh0 = fmaf(0.872f * eh0, rh, 1e-3f);
    float zh1 = fmaf(0.872f * eh1, rh, 1e-3f);
    float th = zh0 + zh1, Ih = th;
    #pragma unroll
    for (int off = 1; off < 64; off <<= 1) {
        float u = __shfl_up(Ih, off, 64);
        if (l >= off) Ih += u;
    }
    float Eh = Ih - th;                          // cumH[i0]
    float ch1 = Eh + zh0;                        // cumH[i1]
    float elo0 = fmaf(2.0f, Eh, -1.0f);          // y-knot of bin i0 (i0=0 -> -1 exact)
    float elo1 = fmaf(2.0f, ch1, -1.0f);
    float h0 = 2.0f * zh0;
    float h1 = (i1 == NB - 1) ? 2.0f * (1.0f - ch1) : 2.0f * zh1;

    // ---------------- derivatives: MIN_D + softplus(pad(ud)) ----------------
    float du0 = (i0 == 0) ? DEF : ud[c * (NB - 1) + i0 - 1];
    float du1 = ud[c * (NB - 1) + i1 - 1];
    float s0 = 1e-3f + log1pf(expf(du0));        // sdv[i0]
    float s1 = 1e-3f + log1pf(expf(du1));        // sdv[i1]
    float s2 = __shfl_down(s0, 1, 64);           // sdv[i1+1] from lane l+1
    if (l == 63) s2 = DSP;                       // sdv[128]

    float dl0 = h0 / w0, dl1 = h1 / w1;
    float T0 = s0 + s1 - 2.0f * dl0;
    float T1 = s1 + s2 - 2.0f * dl1;

    // ---------------- emit records (16 B, single b128-readable) -------------
    // {e_lo f32, h f32, dl f32, d0|T f16x2}
    uint4* g_rec = reinterpret_cast<uint4*>(ws);
    g_rec[c * 129 + i0] = make_uint4(__float_as_uint(elo0), __float_as_uint(h0),
                                     __float_as_uint(dl0), f2h(s0) | (f2h(T0) << 16));
    g_rec[c * 129 + i1] = make_uint4(__float_as_uint(elo1), __float_as_uint(h1),
                                     __float_as_uint(dl1), f2h(s1) | (f2h(T1) << 16));
    if (l == 63)   // pad entry 128 (unreachable; keep defined & safe)
        g_rec[c * 129 + 128] = make_uint4(__float_as_uint(1.0f), __float_as_uint(1.0f),
                                          __float_as_uint(1.0f), f2h(1.0f));

    // ---------------- knots to LDS, then hint16 table -----------------------
    __shared__ float kn[129];
    kn[i0] = elo0;
    kn[i1] = elo1;
    if (l == 63) kn[128] = 1.0f;
    __syncthreads();

    // hint16[s] = k | split<<7.  k = max bin with kn[k] <= slot_left.
    // split = clamp(ceil((kn[k+1]-left)*2^18) - 1, 0, 511); advance iff q>split.
    unsigned short* g_hint = reinterpret_cast<unsigned short*>(
        reinterpret_cast<char*>(ws) + HINT_B);
    for (int s = l; s < NSLOT; s += 64) {
        float left = (float)s * (2.0f / NSLOT) - 1.0f;
        int k = 0;
        #pragma unroll
        for (int st = 64; st >= 1; st >>= 1) {   // 64+...+1 = 127, stays in [0,127]
            int t = k + st;
            if (kn[t] <= left) k = t;
        }
        float X = (kn[k + 1] - left) * 262144.0f;
        int split = (int)ceilf(X) - 1;
        split = split < 0 ? 0 : (split > 511 ? 511 : split);
        g_hint[c * NSLOT + s] = (unsigned short)(k | (split << 7));
    }
}

__global__ __launch_bounds__(256, 4) void spline_main(
    const float4* __restrict__ x4, float4* __restrict__ out4,
    const float* __restrict__ ws, int npair)
{
    __shared__ __align__(16) float tab[TAB_FLOATS];
    {
        float4* dst = reinterpret_cast<float4*>(tab);
        const float4* src = reinterpret_cast<const float4*>(ws);
        for (int t = threadIdx.x; t < TAB_FLOATS / 4; t += 256) dst[t] = src[t];
    }
    __syncthreads();
    const uint4* rp = reinterpret_cast<const uint4*>(tab);
    const unsigned short* hint = reinterpret_cast<const unsigned short*>(
        reinterpret_cast<const char*>(tab) + HINT_B);

    const float LOG_HALF = -0.6931471805599453f;
    const float LN2 = 0.6931471805599453f;
    const int tid = blockIdx.x * 256 + threadIdx.x;
    const int stride = gridDim.x * 256;

    float4 pfa, pfb;
    if (tid < npair) { pfa = x4[2 * tid]; pfb = x4[2 * tid + 1]; }

    for (int i = tid; i < npair; i += stride) {
        float4 xa = pfa, xb = pfb;
        int inx = i + stride;
        inx = (inx < npair) ? inx : i;          // safe redundant prefetch on last iter
        pfa = x4[2 * inx];
        pfb = x4[2 * inx + 1];

        float xs[8] = {xa.x, xa.y, xa.z, xa.w, xb.x, xb.y, xb.z, xb.w};
        float rs[8];

        #pragma unroll
        for (int j = 0; j < 8; ++j) {           // j == channel (flat % 8)
            float xin = xs[j];
            float xc = __builtin_amdgcn_fmed3f(xin, -1.0f, 1.0f);
            float g = fmaf(xc, 262144.0f, 262144.0f);    // (xc+1)*2^18
            int gi = (int)g;
            gi = gi > 524287 ? 524287 : gi;
            int q = gi & 511;
            unsigned hv = hint[j * NSLOT + (gi >> 9)];
            int k2 = (int)(hv & 127u) + ((q > (int)(hv >> 7)) ? 1 : 0);

            uint4 pr = rp[j * 129 + k2];         // ONE ds_read_b128
            float e_lo = __uint_as_float(pr.x);
            float h    = __uint_as_float(pr.y);
            float dl   = __uint_as_float(pr.z);  // f32: no convert, exact
            float d0 = h16lo(pr.w), T = h16hi(pr.w);

            float dy  = __builtin_amdgcn_fmed3f(xc - e_lo, 0.0f, h); // theta in [0,1]
            float dyt = dy * T;
            float a   = fmaf(h, dl - d0, dyt);
            float b   = fmaf(h, d0, -dyt);
            float cp  = dl * dy;
            float a4  = 4.0f * a;
            float disc = fmaxf(fmaf(a4, cp, b * b), 0.0f);
            float sq  = __builtin_amdgcn_sqrtf(disc);
            float t2  = b + sq;
            float uu  = cp + cp;
            float t2s = t2 * t2;
            float denb = fmaf(T * uu, t2 - uu, dl * t2s);
            float numf = h * denb;
            float den  = (dl * sq) * t2s;
            float la = __log2f(numf) - __log2f(den);
            float lm = (xin == xc) ? LN2 : 0.0f;   // inside <=> clamp no-op
            rs[j] = fmaf(lm, la, LOG_HALF);
        }

        out4[2 * i]     = make_float4(rs[0], rs[1], rs[2], rs[3]);
        out4[2 * i + 1] = make_float4(rs[4], rs[5], rs[6], rs[7]);
    }
}

extern "C" void kernel_launch(void* const* d_in, const int* in_sizes, int n_in,
                              void* d_out, int out_size, void* d_ws, size_t ws_size,
                              hipStream_t stream) {
    const float* x  = (const float*)d_in[0];
    const float* uw = (const float*)d_in[1];
    const float* uh = (const float*)d_in[2];
    const float* ud = (const float*)d_in[3];
    float* ws = (float*)d_ws;

    spline_precompute<<<NCH, 64, 0, stream>>>(uw, uh, ud, ws);

    const int npair = out_size / 8;   // 2,097,152 = 2048*256*4
    spline_main<<<2048, 256, 0, stream>>>(
        (const float4*)x, (float4*)d_out, ws, npair);
}